// Round 4
// baseline (322.705 us; speedup 1.0000x reference)
//
#include <hip/hip_runtime.h>

#define N_NODES  100000
#define N_EDGES  640000
#define IN_C     128
#define HID_C    256
#define OUT_C    128
#define N_GRAPHS 64

#define SCAN_CHUNK 1024
#define SCAN_NB    ((N_NODES + SCAN_CHUNK - 1) / SCAN_CHUNK)   // 98

typedef _Float16 f16;
typedef _Float16 f16x4 __attribute__((ext_vector_type(4)));
typedef _Float16 f16x8 __attribute__((ext_vector_type(8)));
typedef float    f32x4 __attribute__((ext_vector_type(4)));

// ---------------- degree / CSR construction ----------------

__global__ void count_deg_kernel(const int* __restrict__ dst, int* __restrict__ cnt) {
    int e = blockIdx.x * blockDim.x + threadIdx.x;
    if (e < N_EDGES) atomicAdd(&cnt[dst[e]], 1);
}

__global__ void compute_isd_kernel(const int* __restrict__ cnt, float* __restrict__ isd) {
    int v = blockIdx.x * blockDim.x + threadIdx.x;
    if (v < N_NODES) isd[v] = rsqrtf((float)cnt[v] + 1.0f);
}

__global__ __launch_bounds__(256) void scan_partial_kernel(
    const int* __restrict__ cnt, int* __restrict__ offs, int* __restrict__ bsum) {
    __shared__ int buf[256];
    int tid  = threadIdx.x;
    int base = blockIdx.x * SCAN_CHUNK + tid * 4;
    int v[4];
    int s = 0;
    #pragma unroll
    for (int j = 0; j < 4; ++j) {
        v[j] = (base + j < N_NODES) ? cnt[base + j] : 0;
        s += v[j];
    }
    buf[tid] = s;
    __syncthreads();
    #pragma unroll
    for (int off = 1; off < 256; off <<= 1) {
        int t = (tid >= off) ? buf[tid - off] : 0;
        __syncthreads();
        buf[tid] += t;
        __syncthreads();
    }
    int excl = buf[tid] - s;
    if (tid == 255) bsum[blockIdx.x] = buf[255];
    int run = excl;
    #pragma unroll
    for (int j = 0; j < 4; ++j) {
        if (base + j < N_NODES) offs[base + j] = run;
        run += v[j];
    }
}

__global__ __launch_bounds__(256) void scan_bsum_kernel(int* __restrict__ bsum,
                                                        int* __restrict__ total) {
    __shared__ int buf[256];
    int tid = threadIdx.x;
    int v = (tid < SCAN_NB) ? bsum[tid] : 0;
    buf[tid] = v;
    __syncthreads();
    #pragma unroll
    for (int off = 1; off < 256; off <<= 1) {
        int t = (tid >= off) ? buf[tid - off] : 0;
        __syncthreads();
        buf[tid] += t;
        __syncthreads();
    }
    if (tid < SCAN_NB) bsum[tid] = buf[tid] - v;
    if (tid == 255) *total = buf[255];
}

__global__ __launch_bounds__(256) void scan_add_kernel(int* __restrict__ offs,
                                                       const int* __restrict__ bsum) {
    int tid  = threadIdx.x;
    int add  = bsum[blockIdx.x];
    int base = blockIdx.x * SCAN_CHUNK + tid * 4;
    if (base + 3 < N_NODES) {
        int4* p = reinterpret_cast<int4*>(&offs[base]);
        int4 o = *p;
        o.x += add; o.y += add; o.z += add; o.w += add;
        *p = o;
    } else {
        for (int j = 0; j < 4; ++j)
            if (base + j < N_NODES) offs[base + j] += add;
    }
}

// csr entries hold (src, coef) so the agg inner loop does one 8B broadcast
__global__ void fill_csr_kernel(const int* __restrict__ src, const int* __restrict__ dst,
                                const int* __restrict__ offs, int* __restrict__ cursor,
                                const float* __restrict__ isd, int2* __restrict__ csr) {
    int e = blockIdx.x * blockDim.x + threadIdx.x;
    if (e < N_EDGES) {
        int d  = dst[e];
        int sv = src[e];
        int pos = offs[d] + atomicAdd(&cursor[d], 1);
        float c = isd[sv] * isd[d];
        csr[pos] = make_int2(sv, __float_as_int(c));
    }
}

// ---------------- fp32 -> fp16 convert (n divisible by 8) ----------------

__global__ void convert_f16_kernel(const float* __restrict__ in, f16* __restrict__ out, int n) {
    int i = (blockIdx.x * blockDim.x + threadIdx.x) * 8;
    if (i < n) {
        float4 a = *reinterpret_cast<const float4*>(&in[i]);
        float4 b = *reinterpret_cast<const float4*>(&in[i + 4]);
        f16x8 o = { (f16)a.x, (f16)a.y, (f16)a.z, (f16)a.w,
                    (f16)b.x, (f16)b.y, (f16)b.z, (f16)b.w };
        *reinterpret_cast<f16x8*>(&out[i]) = o;
    }
}

// W[K][N] fp32 -> Wt[N][K] f16
template <int K, int N>
__global__ void transpose_w_kernel(const float* __restrict__ W, f16* __restrict__ Wt) {
    int idx = blockIdx.x * blockDim.x + threadIdx.x;
    if (idx < K * N) {
        int k = idx / N, n = idx % N;
        Wt[n * K + k] = (f16)W[idx];
    }
}

// ---------------- LDS-free register MFMA GEMM: C[M,N] = A[M,K] @ Wt[N,K]^T --
// 256 thr = 4 waves; wave owns 32 rows (2 row-tiles), A-frags held in VGPRs,
// B-frags streamed from global (W is L2-resident, shared by all blocks).

template <int N, int K, bool BIAS_RELU>
__global__ __launch_bounds__(256) void gemm_reg_kernel(
    const f16* __restrict__ A, const f16* __restrict__ Wt,
    const float* __restrict__ bias, f16* __restrict__ Cmat, int M) {
    constexpr int KS = K / 32;       // k-steps
    constexpr int NT = N / 16;       // col tiles
    constexpr int RT = 2;            // row tiles per wave
    int tid  = threadIdx.x;
    int wid  = tid >> 6;
    int lane = tid & 63;
    int l16  = lane & 15;
    int kgrp = lane >> 4;            // 0..3
    int rowbase = blockIdx.x * 128 + wid * 32;

    f16x8 a[RT][KS];
    f16x8 zero = {};
    #pragma unroll
    for (int rt = 0; rt < RT; ++rt) {
        int r = rowbase + rt * 16 + l16;
        bool ok = r < M;
        #pragma unroll
        for (int s = 0; s < KS; ++s)
            a[rt][s] = ok ? *reinterpret_cast<const f16x8*>(&A[(size_t)r * K + s * 32 + kgrp * 8])
                          : zero;
    }

    #pragma unroll
    for (int c = 0; c < NT; ++c) {
        f32x4 acc[RT] = {};
        #pragma unroll
        for (int s = 0; s < KS; ++s) {
            f16x8 b = *reinterpret_cast<const f16x8*>(
                &Wt[(size_t)(c * 16 + l16) * K + s * 32 + kgrp * 8]);
            #pragma unroll
            for (int rt = 0; rt < RT; ++rt)
                acc[rt] = __builtin_amdgcn_mfma_f32_16x16x32_f16(a[rt][s], b, acc[rt], 0, 0, 0);
        }
        // C/D layout: col = lane&15, row = (lane>>4)*4 + reg  [m89-verified]
        int col = c * 16 + l16;
        float bv = BIAS_RELU ? bias[col] : 0.f;
        #pragma unroll
        for (int rt = 0; rt < RT; ++rt) {
            int crow0 = rowbase + rt * 16 + kgrp * 4;
            #pragma unroll
            for (int j = 0; j < 4; ++j) {
                int row = crow0 + j;
                if (row < M) {
                    float v = acc[rt][j];
                    if constexpr (BIAS_RELU) v = fmaxf(v + bv, 0.f);
                    Cmat[(size_t)row * N + col] = (f16)v;
                }
            }
        }
    }
}

// ---------------- aggregation over C=128 f16 channels ----------------

template <bool BIAS_RELU, typename OutT>
__global__ __launch_bounds__(256) void agg_kernel(
    const f16* __restrict__ h, const int* __restrict__ offs,
    const int2* __restrict__ csr, const float* __restrict__ isd,
    const float* __restrict__ bias, OutT* __restrict__ out) {
    constexpr int C = 128;
    int wid  = threadIdx.x >> 6;
    int lane = threadIdx.x & 63;
    int half = lane >> 5;
    int ln   = lane & 31;
    int v = blockIdx.x * 4 + wid;
    if (v >= N_NODES) return;
    int s = offs[v], e = offs[v + 1];
    float acc[4] = {};
    for (int t = s + half; t < e; t += 2) {
        int2 ec = csr[t];
        float c = __int_as_float(ec.y);
        f16x4 hv = *reinterpret_cast<const f16x4*>(&h[(size_t)ec.x * C + ln * 4]);
        #pragma unroll
        for (int j = 0; j < 4; ++j) acc[j] += c * (float)hv[j];
    }
    #pragma unroll
    for (int j = 0; j < 4; ++j) acc[j] += __shfl_xor(acc[j], 32, 64);
    if (half == 0) {
        float iv = isd[v];
        float cs = iv * iv;
        f16x4 hv = *reinterpret_cast<const f16x4*>(&h[(size_t)v * C + ln * 4]);
        if constexpr (BIAS_RELU) {
            float4 b = *reinterpret_cast<const float4*>(&bias[ln * 4]);
            float4 r;
            r.x = fmaxf(acc[0] + cs * (float)hv[0] + b.x, 0.f);
            r.y = fmaxf(acc[1] + cs * (float)hv[1] + b.y, 0.f);
            r.z = fmaxf(acc[2] + cs * (float)hv[2] + b.z, 0.f);
            r.w = fmaxf(acc[3] + cs * (float)hv[3] + b.w, 0.f);
            *reinterpret_cast<float4*>(&out[(size_t)v * C + ln * 4]) = r;
        } else {
            f16x4 r = { (f16)(acc[0] + cs * (float)hv[0]),
                        (f16)(acc[1] + cs * (float)hv[1]),
                        (f16)(acc[2] + cs * (float)hv[2]),
                        (f16)(acc[3] + cs * (float)hv[3]) };
            *reinterpret_cast<f16x4*>(&out[(size_t)v * C + ln * 4]) = r;
        }
    }
}

// ---------------- global mean pool (batch is sorted) ----------------

__global__ void init_gs_kernel(int* gs) {
    int g = threadIdx.x;
    if (g <= N_GRAPHS) gs[g] = N_NODES;
}

__global__ void find_gs_kernel(const int* __restrict__ batch, int* __restrict__ gs) {
    int i = blockIdx.x * blockDim.x + threadIdx.x;
    if (i >= N_NODES) return;
    int b  = batch[i];
    int pb = (i == 0) ? -1 : batch[i - 1];
    for (int g = pb + 1; g <= b; ++g) gs[g] = i;
}

#define POOL_PARTS 16
__global__ void pool_partial_kernel(const float* __restrict__ h, const int* __restrict__ gs,
                                    float* __restrict__ sums) {
    int g    = blockIdx.x >> 4;
    int part = blockIdx.x & 15;
    int ch   = threadIdx.x;
    int s = gs[g], e = gs[g + 1];
    float acc = 0.f;
    for (int i = s + part; i < e; i += POOL_PARTS)
        acc += h[(size_t)i * OUT_C + ch];
    atomicAdd(&sums[g * OUT_C + ch], acc);
}

__global__ void pool_final_kernel(const float* __restrict__ sums, const int* __restrict__ gs,
                                  float* __restrict__ out2) {
    int g = blockIdx.x, ch = threadIdx.x;
    int c = gs[g + 1] - gs[g];
    out2[g * OUT_C + ch] = sums[g * OUT_C + ch] / fmaxf((float)c, 1.0f);
}

// ---------------- launch ----------------

extern "C" void kernel_launch(void* const* d_in, const int* in_sizes, int n_in,
                              void* d_out, int out_size, void* d_ws, size_t ws_size,
                              hipStream_t stream) {
    const float* x     = (const float*)d_in[0];
    const int*   ei    = (const int*)d_in[1];
    const int*   src   = ei;
    const int*   dst   = ei + N_EDGES;
    const int*   batch = (const int*)d_in[2];
    const float* W1    = (const float*)d_in[3];
    const float* b1    = (const float*)d_in[4];
    const float* W2    = (const float*)d_in[5];
    const float* b2    = (const float*)d_in[6];

    float* out    = (float*)d_out;
    float* h_out  = out;                                  // [N_NODES, OUT_C]
    float* ge_out = out + (size_t)N_NODES * OUT_C;        // [N_GRAPHS, OUT_C]

    char* wsp = (char*)d_ws;
    auto alloc = [&](size_t bytes) -> char* {
        char* p = wsp;
        wsp += (bytes + 255) & ~(size_t)255;
        return p;
    };
    int*   cnt     = (int*)alloc((size_t)N_NODES * 4);
    int*   offs    = (int*)alloc((size_t)(N_NODES + 1) * 4);
    int*   cursor  = (int*)alloc((size_t)N_NODES * 4);
    float* isd     = (float*)alloc((size_t)N_NODES * 4);
    int2*  csr     = (int2*)alloc((size_t)N_EDGES * 8);
    int*   bsum    = (int*)alloc((size_t)SCAN_NB * 4);
    int*   gs      = (int*)alloc((size_t)(N_GRAPHS + 1) * 4);
    float* sums    = (float*)alloc((size_t)N_GRAPHS * OUT_C * 4);
    f16*   xh      = (f16*)alloc((size_t)N_NODES * IN_C * 2);
    f16*   ax      = (f16*)alloc((size_t)N_NODES * IN_C * 2);
    f16*   t1      = (f16*)alloc((size_t)N_NODES * HID_C * 2);
    f16*   t2      = (f16*)alloc((size_t)N_NODES * OUT_C * 2);
    f16*   Wt1     = (f16*)alloc((size_t)IN_C * HID_C * 2);
    f16*   Wt2     = (f16*)alloc((size_t)HID_C * OUT_C * 2);

    hipMemsetAsync(cnt,    0, (size_t)N_NODES * 4, stream);
    hipMemsetAsync(cursor, 0, (size_t)N_NODES * 4, stream);
    hipMemsetAsync(sums,   0, (size_t)N_GRAPHS * OUT_C * 4, stream);

    // CSR build
    count_deg_kernel<<<(N_EDGES + 255) / 256, 256, 0, stream>>>(dst, cnt);
    compute_isd_kernel<<<(N_NODES + 255) / 256, 256, 0, stream>>>(cnt, isd);
    scan_partial_kernel<<<SCAN_NB, 256, 0, stream>>>(cnt, offs, bsum);
    scan_bsum_kernel<<<1, 256, 0, stream>>>(bsum, offs + N_NODES);
    scan_add_kernel<<<SCAN_NB, 256, 0, stream>>>(offs, bsum);
    fill_csr_kernel<<<(N_EDGES + 255) / 256, 256, 0, stream>>>(src, dst, offs, cursor, isd, csr);

    // precision prep
    convert_f16_kernel<<<(N_NODES * IN_C / 8 + 255) / 256, 256, 0, stream>>>(
        x, xh, N_NODES * IN_C);
    transpose_w_kernel<IN_C, HID_C><<<(IN_C * HID_C + 255) / 256, 256, 0, stream>>>(W1, Wt1);
    transpose_w_kernel<HID_C, OUT_C><<<(HID_C * OUT_C + 255) / 256, 256, 0, stream>>>(W2, Wt2);

    // layer 1: agg(x) then relu(. @ W1 + b1)   [agg is linear: agg(xW) = agg(x)W]
    agg_kernel<false, f16><<<(N_NODES + 3) / 4, 256, 0, stream>>>(
        xh, offs, csr, isd, nullptr, ax);
    gemm_reg_kernel<HID_C, IN_C, true><<<(N_NODES + 127) / 128, 256, 0, stream>>>(
        ax, Wt1, b1, t1, N_NODES);

    // layer 2: t2 = t1 @ W2, then relu(agg(t2) + b2)
    gemm_reg_kernel<OUT_C, HID_C, false><<<(N_NODES + 127) / 128, 256, 0, stream>>>(
        t1, Wt2, nullptr, t2, N_NODES);
    agg_kernel<true, float><<<(N_NODES + 3) / 4, 256, 0, stream>>>(
        t2, offs, csr, isd, b2, h_out);

    // pool
    init_gs_kernel<<<1, N_GRAPHS + 1, 0, stream>>>(gs);
    find_gs_kernel<<<(N_NODES + 255) / 256, 256, 0, stream>>>(batch, gs);
    pool_partial_kernel<<<N_GRAPHS * POOL_PARTS, OUT_C, 0, stream>>>(h_out, gs, sums);
    pool_final_kernel<<<N_GRAPHS, OUT_C, 0, stream>>>(sums, gs, ge_out);
}

// Round 5
// 297.142 us; speedup vs baseline: 1.0860x; 1.0860x over previous
//
#include <hip/hip_runtime.h>

#define N_NODES  100000
#define N_EDGES  640000
#define IN_C     128
#define HID_C    256
#define OUT_C    128
#define N_GRAPHS 64

#define SCAN_CHUNK 1024
#define SCAN_NB    ((N_NODES + SCAN_CHUNK - 1) / SCAN_CHUNK)   // 98

typedef _Float16 f16;
typedef _Float16 f16x4 __attribute__((ext_vector_type(4)));
typedef _Float16 f16x8 __attribute__((ext_vector_type(8)));
typedef float    f32x4 __attribute__((ext_vector_type(4)));

// ---------------- degree / CSR construction ----------------

__global__ void count_deg_kernel(const int* __restrict__ dst, int* __restrict__ cnt) {
    int e = blockIdx.x * blockDim.x + threadIdx.x;
    if (e < N_EDGES) atomicAdd(&cnt[dst[e]], 1);
}

__global__ void compute_isd_kernel(const int* __restrict__ cnt, float* __restrict__ isd) {
    int v = blockIdx.x * blockDim.x + threadIdx.x;
    if (v < N_NODES) isd[v] = rsqrtf((float)cnt[v] + 1.0f);
}

__global__ __launch_bounds__(256) void scan_partial_kernel(
    const int* __restrict__ cnt, int* __restrict__ offs, int* __restrict__ bsum) {
    __shared__ int buf[256];
    int tid  = threadIdx.x;
    int base = blockIdx.x * SCAN_CHUNK + tid * 4;
    int v[4];
    int s = 0;
    #pragma unroll
    for (int j = 0; j < 4; ++j) {
        v[j] = (base + j < N_NODES) ? cnt[base + j] : 0;
        s += v[j];
    }
    buf[tid] = s;
    __syncthreads();
    #pragma unroll
    for (int off = 1; off < 256; off <<= 1) {
        int t = (tid >= off) ? buf[tid - off] : 0;
        __syncthreads();
        buf[tid] += t;
        __syncthreads();
    }
    int excl = buf[tid] - s;
    if (tid == 255) bsum[blockIdx.x] = buf[255];
    int run = excl;
    #pragma unroll
    for (int j = 0; j < 4; ++j) {
        if (base + j < N_NODES) offs[base + j] = run;
        run += v[j];
    }
}

__global__ __launch_bounds__(256) void scan_bsum_kernel(int* __restrict__ bsum,
                                                        int* __restrict__ total) {
    __shared__ int buf[256];
    int tid = threadIdx.x;
    int v = (tid < SCAN_NB) ? bsum[tid] : 0;
    buf[tid] = v;
    __syncthreads();
    #pragma unroll
    for (int off = 1; off < 256; off <<= 1) {
        int t = (tid >= off) ? buf[tid - off] : 0;
        __syncthreads();
        buf[tid] += t;
        __syncthreads();
    }
    if (tid < SCAN_NB) bsum[tid] = buf[tid] - v;
    if (tid == 255) *total = buf[255];
}

__global__ __launch_bounds__(256) void scan_add_kernel(int* __restrict__ offs,
                                                       const int* __restrict__ bsum) {
    int tid  = threadIdx.x;
    int add  = bsum[blockIdx.x];
    int base = blockIdx.x * SCAN_CHUNK + tid * 4;
    if (base + 3 < N_NODES) {
        int4* p = reinterpret_cast<int4*>(&offs[base]);
        int4 o = *p;
        o.x += add; o.y += add; o.z += add; o.w += add;
        *p = o;
    } else {
        for (int j = 0; j < 4; ++j)
            if (base + j < N_NODES) offs[base + j] += add;
    }
}

// csr entries hold (src, coef) so the agg inner loop does one 8B broadcast
__global__ void fill_csr_kernel(const int* __restrict__ src, const int* __restrict__ dst,
                                const int* __restrict__ offs, int* __restrict__ cursor,
                                const float* __restrict__ isd, int2* __restrict__ csr) {
    int e = blockIdx.x * blockDim.x + threadIdx.x;
    if (e < N_EDGES) {
        int d  = dst[e];
        int sv = src[e];
        int pos = offs[d] + atomicAdd(&cursor[d], 1);
        float c = isd[sv] * isd[d];
        csr[pos] = make_int2(sv, __float_as_int(c));
    }
}

// ---------------- fp32 -> fp16 convert (n divisible by 8) ----------------

__global__ void convert_f16_kernel(const float* __restrict__ in, f16* __restrict__ out, int n) {
    int i = (blockIdx.x * blockDim.x + threadIdx.x) * 8;
    if (i < n) {
        float4 a = *reinterpret_cast<const float4*>(&in[i]);
        float4 b = *reinterpret_cast<const float4*>(&in[i + 4]);
        f16x8 o = { (f16)a.x, (f16)a.y, (f16)a.z, (f16)a.w,
                    (f16)b.x, (f16)b.y, (f16)b.z, (f16)b.w };
        *reinterpret_cast<f16x8*>(&out[i]) = o;
    }
}

// W[K][N] fp32 -> Wt[N][K] f16
template <int K, int N>
__global__ void transpose_w_kernel(const float* __restrict__ W, f16* __restrict__ Wt) {
    int idx = blockIdx.x * blockDim.x + threadIdx.x;
    if (idx < K * N) {
        int k = idx / N, n = idx % N;
        Wt[n * K + k] = (f16)W[idx];
    }
}

// ---------------- LDS-free register MFMA GEMM: C[M,N] = A[M,K] @ Wt[N,K]^T --

template <int N, int K, bool BIAS_RELU>
__global__ __launch_bounds__(256) void gemm_reg_kernel(
    const f16* __restrict__ A, const f16* __restrict__ Wt,
    const float* __restrict__ bias, f16* __restrict__ Cmat, int M) {
    constexpr int KS = K / 32;       // k-steps
    constexpr int NT = N / 16;       // col tiles
    constexpr int RT = 2;            // row tiles per wave
    int tid  = threadIdx.x;
    int wid  = tid >> 6;
    int lane = tid & 63;
    int l16  = lane & 15;
    int kgrp = lane >> 4;            // 0..3
    int rowbase = blockIdx.x * 128 + wid * 32;

    f16x8 a[RT][KS];
    f16x8 zero = {};
    #pragma unroll
    for (int rt = 0; rt < RT; ++rt) {
        int r = rowbase + rt * 16 + l16;
        bool ok = r < M;
        #pragma unroll
        for (int s = 0; s < KS; ++s)
            a[rt][s] = ok ? *reinterpret_cast<const f16x8*>(&A[(size_t)r * K + s * 32 + kgrp * 8])
                          : zero;
    }

    #pragma unroll
    for (int c = 0; c < NT; ++c) {
        f32x4 acc[RT] = {};
        #pragma unroll
        for (int s = 0; s < KS; ++s) {
            f16x8 b = *reinterpret_cast<const f16x8*>(
                &Wt[(size_t)(c * 16 + l16) * K + s * 32 + kgrp * 8]);
            #pragma unroll
            for (int rt = 0; rt < RT; ++rt)
                acc[rt] = __builtin_amdgcn_mfma_f32_16x16x32_f16(a[rt][s], b, acc[rt], 0, 0, 0);
        }
        // C/D layout: col = lane&15, row = (lane>>4)*4 + reg  [m89-verified]
        int col = c * 16 + l16;
        float bv = BIAS_RELU ? bias[col] : 0.f;
        #pragma unroll
        for (int rt = 0; rt < RT; ++rt) {
            int crow0 = rowbase + rt * 16 + kgrp * 4;
            #pragma unroll
            for (int j = 0; j < 4; ++j) {
                int row = crow0 + j;
                if (row < M) {
                    float v = acc[rt][j];
                    if constexpr (BIAS_RELU) v = fmaxf(v + bv, 0.f);
                    Cmat[(size_t)row * N + col] = (f16)v;
                }
            }
        }
    }
}

// ---------------- aggregation over C=128 f16 channels ----------------
// 1 wave per node; 4 edges in flight (16-lane quarters, f16x8 = 16B/lane),
// manual 2x unroll for 8 in-flight gathers on high-degree nodes.

template <bool BIAS_RELU, typename OutT>
__global__ __launch_bounds__(256) void agg_kernel(
    const f16* __restrict__ h, const int* __restrict__ offs,
    const int2* __restrict__ csr, const float* __restrict__ isd,
    const float* __restrict__ bias, OutT* __restrict__ out) {
    constexpr int C = 128;
    int wid  = threadIdx.x >> 6;
    int lane = threadIdx.x & 63;
    int q    = lane >> 4;            // edge slot 0..3
    int ln   = lane & 15;            // 8 channels per lane
    int v = blockIdx.x * 4 + wid;
    if (v >= N_NODES) return;
    int s = offs[v], e = offs[v + 1];
    float acc[8] = {};
    int t = s + q;
    for (; t + 4 < e; t += 8) {      // 2 edges per quarter in flight
        int2 e0 = csr[t];
        int2 e1 = csr[t + 4];
        float c0 = __int_as_float(e0.y);
        float c1 = __int_as_float(e1.y);
        f16x8 h0 = *reinterpret_cast<const f16x8*>(&h[(size_t)e0.x * C + ln * 8]);
        f16x8 h1 = *reinterpret_cast<const f16x8*>(&h[(size_t)e1.x * C + ln * 8]);
        #pragma unroll
        for (int j = 0; j < 8; ++j) acc[j] += c0 * (float)h0[j] + c1 * (float)h1[j];
    }
    if (t < e) {
        int2 e0 = csr[t];
        float c0 = __int_as_float(e0.y);
        f16x8 h0 = *reinterpret_cast<const f16x8*>(&h[(size_t)e0.x * C + ln * 8]);
        #pragma unroll
        for (int j = 0; j < 8; ++j) acc[j] += c0 * (float)h0[j];
    }
    // reduce across the 4 quarter-groups (same ln)
    #pragma unroll
    for (int j = 0; j < 8; ++j) {
        acc[j] += __shfl_xor(acc[j], 16, 64);
        acc[j] += __shfl_xor(acc[j], 32, 64);
    }
    if (q == 0) {
        float iv = isd[v];
        float cs = iv * iv;
        f16x8 hv = *reinterpret_cast<const f16x8*>(&h[(size_t)v * C + ln * 8]);
        if constexpr (BIAS_RELU) {
            float4 b0 = *reinterpret_cast<const float4*>(&bias[ln * 8]);
            float4 b1 = *reinterpret_cast<const float4*>(&bias[ln * 8 + 4]);
            float bb[8] = {b0.x, b0.y, b0.z, b0.w, b1.x, b1.y, b1.z, b1.w};
            float r[8];
            #pragma unroll
            for (int j = 0; j < 8; ++j)
                r[j] = fmaxf(acc[j] + cs * (float)hv[j] + bb[j], 0.f);
            *reinterpret_cast<float4*>(&out[(size_t)v * C + ln * 8]) =
                make_float4(r[0], r[1], r[2], r[3]);
            *reinterpret_cast<float4*>(&out[(size_t)v * C + ln * 8 + 4]) =
                make_float4(r[4], r[5], r[6], r[7]);
        } else {
            f16x8 r;
            #pragma unroll
            for (int j = 0; j < 8; ++j)
                r[j] = (f16)(acc[j] + cs * (float)hv[j]);
            *reinterpret_cast<f16x8*>(&out[(size_t)v * C + ln * 8]) = r;
        }
    }
}

// ---------------- global mean pool (batch is sorted) ----------------

__global__ void init_gs_kernel(int* gs) {
    int g = threadIdx.x;
    if (g <= N_GRAPHS) gs[g] = N_NODES;
}

__global__ void find_gs_kernel(const int* __restrict__ batch, int* __restrict__ gs) {
    int i = blockIdx.x * blockDim.x + threadIdx.x;
    if (i >= N_NODES) return;
    int b  = batch[i];
    int pb = (i == 0) ? -1 : batch[i - 1];
    for (int g = pb + 1; g <= b; ++g) gs[g] = i;
}

#define POOL_PARTS 16
__global__ void pool_partial_kernel(const float* __restrict__ h, const int* __restrict__ gs,
                                    float* __restrict__ sums) {
    int g    = blockIdx.x >> 4;
    int part = blockIdx.x & 15;
    int ch   = threadIdx.x;
    int s = gs[g], e = gs[g + 1];
    float acc = 0.f;
    for (int i = s + part; i < e; i += POOL_PARTS)
        acc += h[(size_t)i * OUT_C + ch];
    atomicAdd(&sums[g * OUT_C + ch], acc);
}

__global__ void pool_final_kernel(const float* __restrict__ sums, const int* __restrict__ gs,
                                  float* __restrict__ out2) {
    int g = blockIdx.x, ch = threadIdx.x;
    int c = gs[g + 1] - gs[g];
    out2[g * OUT_C + ch] = sums[g * OUT_C + ch] / fmaxf((float)c, 1.0f);
}

// ---------------- launch ----------------

extern "C" void kernel_launch(void* const* d_in, const int* in_sizes, int n_in,
                              void* d_out, int out_size, void* d_ws, size_t ws_size,
                              hipStream_t stream) {
    const float* x     = (const float*)d_in[0];
    const int*   ei    = (const int*)d_in[1];
    const int*   src   = ei;
    const int*   dst   = ei + N_EDGES;
    const int*   batch = (const int*)d_in[2];
    const float* W1    = (const float*)d_in[3];
    const float* b1    = (const float*)d_in[4];
    const float* W2    = (const float*)d_in[5];
    const float* b2    = (const float*)d_in[6];

    float* out    = (float*)d_out;
    float* h_out  = out;                                  // [N_NODES, OUT_C]
    float* ge_out = out + (size_t)N_NODES * OUT_C;        // [N_GRAPHS, OUT_C]

    char* wsp = (char*)d_ws;
    auto alloc = [&](size_t bytes) -> char* {
        char* p = wsp;
        wsp += (bytes + 255) & ~(size_t)255;
        return p;
    };
    int*   cnt     = (int*)alloc((size_t)N_NODES * 4);
    int*   offs    = (int*)alloc((size_t)(N_NODES + 1) * 4);
    int*   cursor  = (int*)alloc((size_t)N_NODES * 4);
    float* isd     = (float*)alloc((size_t)N_NODES * 4);
    int2*  csr     = (int2*)alloc((size_t)N_EDGES * 8);
    int*   bsum    = (int*)alloc((size_t)SCAN_NB * 4);
    int*   gs      = (int*)alloc((size_t)(N_GRAPHS + 1) * 4);
    float* sums    = (float*)alloc((size_t)N_GRAPHS * OUT_C * 4);
    f16*   xh      = (f16*)alloc((size_t)N_NODES * IN_C * 2);
    f16*   ax      = (f16*)alloc((size_t)N_NODES * IN_C * 2);
    f16*   t1      = (f16*)alloc((size_t)N_NODES * HID_C * 2);
    f16*   t2      = (f16*)alloc((size_t)N_NODES * OUT_C * 2);
    f16*   Wt1     = (f16*)alloc((size_t)IN_C * HID_C * 2);
    f16*   Wt2     = (f16*)alloc((size_t)HID_C * OUT_C * 2);

    hipMemsetAsync(cnt,    0, (size_t)N_NODES * 4, stream);
    hipMemsetAsync(cursor, 0, (size_t)N_NODES * 4, stream);
    hipMemsetAsync(sums,   0, (size_t)N_GRAPHS * OUT_C * 4, stream);

    // CSR build
    count_deg_kernel<<<(N_EDGES + 255) / 256, 256, 0, stream>>>(dst, cnt);
    compute_isd_kernel<<<(N_NODES + 255) / 256, 256, 0, stream>>>(cnt, isd);
    scan_partial_kernel<<<SCAN_NB, 256, 0, stream>>>(cnt, offs, bsum);
    scan_bsum_kernel<<<1, 256, 0, stream>>>(bsum, offs + N_NODES);
    scan_add_kernel<<<SCAN_NB, 256, 0, stream>>>(offs, bsum);
    fill_csr_kernel<<<(N_EDGES + 255) / 256, 256, 0, stream>>>(src, dst, offs, cursor, isd, csr);

    // precision prep
    convert_f16_kernel<<<(N_NODES * IN_C / 8 + 255) / 256, 256, 0, stream>>>(
        x, xh, N_NODES * IN_C);
    transpose_w_kernel<IN_C, HID_C><<<(IN_C * HID_C + 255) / 256, 256, 0, stream>>>(W1, Wt1);
    transpose_w_kernel<HID_C, OUT_C><<<(HID_C * OUT_C + 255) / 256, 256, 0, stream>>>(W2, Wt2);

    // layer 1: agg(x) then relu(. @ W1 + b1)   [agg is linear: agg(xW) = agg(x)W]
    agg_kernel<false, f16><<<(N_NODES + 3) / 4, 256, 0, stream>>>(
        xh, offs, csr, isd, nullptr, ax);
    gemm_reg_kernel<HID_C, IN_C, true><<<(N_NODES + 127) / 128, 256, 0, stream>>>(
        ax, Wt1, b1, t1, N_NODES);

    // layer 2: t2 = t1 @ W2, then relu(agg(t2) + b2)
    gemm_reg_kernel<OUT_C, HID_C, false><<<(N_NODES + 127) / 128, 256, 0, stream>>>(
        t1, Wt2, nullptr, t2, N_NODES);
    agg_kernel<true, float><<<(N_NODES + 3) / 4, 256, 0, stream>>>(
        t2, offs, csr, isd, b2, h_out);

    // pool
    init_gs_kernel<<<1, N_GRAPHS + 1, 0, stream>>>(gs);
    find_gs_kernel<<<(N_NODES + 255) / 256, 256, 0, stream>>>(batch, gs);
    pool_partial_kernel<<<N_GRAPHS * POOL_PARTS, OUT_C, 0, stream>>>(h_out, gs, sums);
    pool_final_kernel<<<N_GRAPHS, OUT_C, 0, stream>>>(sums, gs, ge_out);
}